// Round 1
// baseline (215.797 us; speedup 1.0000x reference)
//
#include <hip/hip_runtime.h>
#include <math.h>

#define TW 64      // output tile width
#define TH 16      // output tile height
#define RAD 5      // (11-1)/2
#define IW 74      // input tile width  (TW + 10)
#define IH 26      // input tile height (TH + 10)
#define IWP 76     // padded row stride for input tiles (16B-aligned rows)
#define HWP 68     // padded row stride for horizontal-conv fields (16B-aligned rows)
#define IMG 512

struct W11 { float w[11]; };

__device__ __forceinline__ unsigned omap(float f) {
  unsigned b = __float_as_uint(f);
  return (b & 0x80000000u) ? ~b : (b | 0x80000000u);
}
__device__ __forceinline__ float ounmap(unsigned u) {
  return __uint_as_float((u & 0x80000000u) ? (u ^ 0x80000000u) : ~u);
}

__global__ void init_mm(unsigned* ws) {
  if (threadIdx.x == 0) { ws[0] = 0u; ws[1] = 0xFFFFFFFFu; }
}

__global__ __launch_bounds__(256) void minmax_k(const float4* __restrict__ img,
                                                int n4, unsigned* ws) {
  unsigned mx = 0u, mn = 0xFFFFFFFFu;
  int stride = gridDim.x * blockDim.x;
  for (int i = blockIdx.x * blockDim.x + threadIdx.x; i < n4; i += stride) {
    float4 v = img[i];
    unsigned a = omap(v.x), b = omap(v.y), c = omap(v.z), d = omap(v.w);
    mx = max(mx, max(max(a, b), max(c, d)));
    mn = min(mn, min(min(a, b), min(c, d)));
  }
  #pragma unroll
  for (int off = 32; off > 0; off >>= 1) {
    mx = max(mx, __shfl_down(mx, off));
    mn = min(mn, __shfl_down(mn, off));
  }
  __shared__ unsigned smx[4], smn[4];
  int lane = threadIdx.x & 63, wv = threadIdx.x >> 6;
  if (lane == 0) { smx[wv] = mx; smn[wv] = mn; }
  __syncthreads();
  if (threadIdx.x == 0) {
    mx = max(max(smx[0], smx[1]), max(smx[2], smx[3]));
    mn = min(min(smn[0], smn[1]), min(smn[2], smn[3]));
    atomicMax(&ws[0], mx);
    atomicMin(&ws[1], mn);
  }
}

// Fused: stage img1/img2 tile -> horizontal conv of 5 fields -> vertical conv -> SSIM
__global__ __launch_bounds__(256) void ssim_k(const float* __restrict__ img1,
                                              const float* __restrict__ img2,
                                              float* __restrict__ out,
                                              const unsigned* __restrict__ ws,
                                              W11 wv) {
  __shared__ float sIn1[IH][IWP];
  __shared__ float sIn2[IH][IWP];
  __shared__ float sH[5][IH][HWP];   // h-conv of: x1, x2, x1^2, x2^2, x1*x2

  const int tid = threadIdx.x;
  const int bx = blockIdx.x, by = blockIdx.y, n = blockIdx.z;
  const float* p1 = img1 + (size_t)n * IMG * IMG;
  const float* p2 = img2 + (size_t)n * IMG * IMG;
  const int x0 = bx * TW - RAD;
  const int y0 = by * TH - RAD;

  // ---- stage (zero-padded at image borders) ----
  for (int idx = tid; idx < IH * IW; idx += 256) {
    int r = idx / IW, c = idx - r * IW;
    int gx = x0 + c, gy = y0 + r;
    bool ok = (gx >= 0) & (gx < IMG) & (gy >= 0) & (gy < IMG);
    int off = gy * IMG + gx;
    sIn1[r][c] = ok ? p1[off] : 0.f;
    sIn2[r][c] = ok ? p2[off] : 0.f;
  }
  __syncthreads();

  // ---- horizontal pass: 4 consecutive points per thread, float4 LDS reads ----
  for (int g = tid; g < IH * (TW / 4); g += 256) {
    int r = g >> 4;            // h-field row 0..25
    int xg = (g & 15) << 2;    // first of 4 output columns
    float a[16], b[16];
    *(float4*)&a[0]  = *(const float4*)&sIn1[r][xg + 0];
    *(float4*)&a[4]  = *(const float4*)&sIn1[r][xg + 4];
    *(float4*)&a[8]  = *(const float4*)&sIn1[r][xg + 8];
    *(float4*)&a[12] = *(const float4*)&sIn1[r][xg + 12];
    *(float4*)&b[0]  = *(const float4*)&sIn2[r][xg + 0];
    *(float4*)&b[4]  = *(const float4*)&sIn2[r][xg + 4];
    *(float4*)&b[8]  = *(const float4*)&sIn2[r][xg + 8];
    *(float4*)&b[12] = *(const float4*)&sIn2[r][xg + 12];

    float a2[14], b2[14], ab[14];
    #pragma unroll
    for (int t = 0; t < 14; ++t) { a2[t] = a[t]*a[t]; b2[t] = b[t]*b[t]; ab[t] = a[t]*b[t]; }

    float h1[4] = {0,0,0,0}, h2[4] = {0,0,0,0};
    float h11[4] = {0,0,0,0}, h22[4] = {0,0,0,0}, h12[4] = {0,0,0,0};
    #pragma unroll
    for (int k = 0; k < 11; ++k) {
      float wk = wv.w[k];
      #pragma unroll
      for (int j = 0; j < 4; ++j) {
        h1[j]  += wk * a[j + k];
        h2[j]  += wk * b[j + k];
        h11[j] += wk * a2[j + k];
        h22[j] += wk * b2[j + k];
        h12[j] += wk * ab[j + k];
      }
    }
    *(float4*)&sH[0][r][xg] = make_float4(h1[0], h1[1], h1[2], h1[3]);
    *(float4*)&sH[1][r][xg] = make_float4(h2[0], h2[1], h2[2], h2[3]);
    *(float4*)&sH[2][r][xg] = make_float4(h11[0], h11[1], h11[2], h11[3]);
    *(float4*)&sH[3][r][xg] = make_float4(h22[0], h22[1], h22[2], h22[3]);
    *(float4*)&sH[4][r][xg] = make_float4(h12[0], h12[1], h12[2], h12[3]);
  }
  __syncthreads();

  // ---- C1/C2 from global min/max ----
  float L = ounmap(ws[0]) - ounmap(ws[1]);
  if (L == 0.f) L = 5.f;
  float C1 = 0.01f * L; C1 *= C1;
  float C2 = 0.03f * L; C2 *= C2;

  // ---- vertical pass: each thread does one column x, 4 consecutive rows ----
  const int x = tid & 63;
  const int yb = (tid >> 6) * 4;
  float m1[4] = {0,0,0,0}, m2[4] = {0,0,0,0};
  float e11[4] = {0,0,0,0}, e22[4] = {0,0,0,0}, e12[4] = {0,0,0,0};

  #pragma unroll
  for (int f = 0; f < 5; ++f) {
    float v[14];
    #pragma unroll
    for (int i = 0; i < 14; ++i) v[i] = sH[f][yb + i][x];
    float acc[4] = {0,0,0,0};
    #pragma unroll
    for (int k = 0; k < 11; ++k) {
      float wk = wv.w[k];
      #pragma unroll
      for (int j = 0; j < 4; ++j) acc[j] += wk * v[j + k];
    }
    #pragma unroll
    for (int j = 0; j < 4; ++j) {
      if (f == 0) m1[j] = acc[j];
      else if (f == 1) m2[j] = acc[j];
      else if (f == 2) e11[j] = acc[j];
      else if (f == 3) e22[j] = acc[j];
      else e12[j] = acc[j];
    }
  }

  #pragma unroll
  for (int j = 0; j < 4; ++j) {
    float mu1 = m1[j], mu2 = m2[j];
    float mu1s = mu1 * mu1, mu2s = mu2 * mu2, mu12 = mu1 * mu2;
    float s1 = e11[j] - mu1s, s2 = e22[j] - mu2s, s12 = e12[j] - mu12;
    float num = (2.f * mu12 + C1) * (2.f * s12 + C2);
    float den = (mu1s + mu2s + C1) * (s1 + s2 + C2);
    int gy = by * TH + yb + j, gx = bx * TW + x;
    out[(size_t)n * IMG * IMG + (size_t)gy * IMG + gx] = num / den;
  }
}

extern "C" void kernel_launch(void* const* d_in, const int* in_sizes, int n_in,
                              void* d_out, int out_size, void* d_ws, size_t ws_size,
                              hipStream_t stream) {
  const float* img1 = (const float*)d_in[0];
  const float* img2 = (const float*)d_in[1];
  float* out = (float*)d_out;
  unsigned* ws = (unsigned*)d_ws;
  int n = in_sizes[0];             // 32*1*512*512 = 8388608
  int batch = n / (IMG * IMG);     // 32

  // Gaussian window, center at ws/2 = 5.5 (asymmetric!), normalized — matches reference
  W11 wv;
  double g[11], s = 0.0;
  for (int i = 0; i < 11; ++i) { double d = i - 5.5; g[i] = exp(-(d * d) / 4.5); s += g[i]; }
  for (int i = 0; i < 11; ++i) wv.w[i] = (float)(g[i] / s);

  init_mm<<<1, 64, 0, stream>>>(ws);
  minmax_k<<<2048, 256, 0, stream>>>((const float4*)img1, n / 4, ws);
  dim3 grid(IMG / TW, IMG / TH, batch);
  ssim_k<<<grid, 256, 0, stream>>>(img1, img2, out, ws, wv);
}